// Round 10
// baseline (10.933 us; speedup 1.0000x reference)
//
#include <hip/hip_runtime.h>
#include <math.h>

// Problem shape (fixed by the reference setup_inputs): B=4, D=32, H=32, W=16
#define NB 4
#define ND 32
#define NH 32
#define NW 16
#define CPS (ND * NH)            // 1024 (d,h)-columns per sample
#define VPS (CPS * NW)           // 16384 voxels per sample
#define NBLK 256                 // 4 samples x 8 pred-chunks x 8 target-chunks
#define PC 128                   // pred columns per block
#define TC 128                   // target columns per block

// Single-dispatch fused kernel, full chip (256 blocks x 512 threads).
// R9 skeleton (10.9us) + three polish cuts:
//  - Phase A spread over all 512 threads (2 float4/thread, pair shfl-combine)
//  - no s_win/syncthreads: handshake + winner finish live in wave 0 only,
//    eligibility broadcast via in-wave __shfl
//  - second vmcnt drain removed (branch on o1 already orders fcnt after gcnt)
//
// Phase A (all 512): thread pair (2c, 2c+1) covers column c: each loads 2
//   float4 (8 w's), builds an 8-bit occupancy mask (pred: logit > 0 <=>
//   sigmoid > 0.5; target: t > 0.5), combines via __shfl_xor(1) -> 16-bit
//   mask; extremes via ffs/clz -> int2 in LDS (even thread writes).
// Phase B (all 512): thread owns pred col (tid>>2) x 32 target cols
//   (tg + 4i -> 4-address LDS broadcast, conflict-free). FULLY unrolled,
//   compile-time-indexed dd2/dh2 (R8 lesson / rule #20: partial unroll ->
//   runtime index -> scratch spill). w-part q = max(pmax-tmin, tmax-pmin).
// Phase C (wave 0): plain agent store of block max -> bmax[bid]; vmcnt(0)
//   drain; group ticket (16 groups x 16 adds, each counter on its OWN 128B
//   line) -> final ticket (16 adds, own line). Winner test ((old+1)&15)==0
//   fires exactly once per counter per call for ANY start value -> no init,
//   poison- and replay-proof (proven R5-R9). Winner wave: 64 lanes x 4 agent
//   loads of the 256 partials, reduce, sqrt, mean, store.
__global__ __launch_bounds__(512) void hd_one(
    const float* __restrict__ logits, const float* __restrict__ targets,
    int* bmax, unsigned* gcnt, unsigned* fcnt, float* __restrict__ out) {
    __shared__ int2 s_pe[PC];
    __shared__ int2 s_te[TC];
    __shared__ int s_red[8];

    int bid = blockIdx.x;                 // s*64 + pchunk*8 + tchunk
    int s = bid >> 6;
    int pchunk = (bid >> 3) & 7;
    int tchunk = bid & 7;
    int tid = threadIdx.x;                // 0..511

    // ---- Phase A: column extremes (pair of threads per column) ----
    {
        bool isp = tid < 256;
        int lc = (tid >> 1) & (PC - 1);   // column within chunk
        int half = tid & 1;               // which 8 w's
        int col = (isp ? pchunk : tchunk) * PC + lc;
        const float4* p4 =
            (const float4*)((isp ? logits : targets) + s * VPS + col * NW) +
            half * 2;
        float thr = isp ? 0.0f : 0.5f;
        unsigned msk = 0;
#pragma unroll
        for (int j = 0; j < 2; ++j) {
            float4 v = p4[j];
            msk |= (v.x > thr ? 1u : 0u) << (4 * j);
            msk |= (v.y > thr ? 1u : 0u) << (4 * j + 1);
            msk |= (v.z > thr ? 1u : 0u) << (4 * j + 2);
            msk |= (v.w > thr ? 1u : 0u) << (4 * j + 3);
        }
        msk <<= 8 * half;
        msk |= __shfl_xor(msk, 1, 64);    // pair shares a wave (pairs never
                                          // straddle a 64-lane boundary)
        if (half == 0) {
            int2 e = make_int2(msk ? (__ffs(msk) - 1) : 1000,
                               msk ? (31 - __clz(msk)) : -1);
            if (isp) s_pe[lc] = e; else s_te[lc] = e;
        }
    }
    __syncthreads();

    // ---- Phase B: pair max (fully unrolled; register-indexed dd2/dh2) ----
    int lp = tid >> 2;                    // local pred column 0..127
    int tg = tid & 3;
    int2 pe = s_pe[lp];
    int pcol = pchunk * PC + lp;
    int pd = pcol >> 5, ph = pcol & 31;

    int dd2[4], dh2[8];
#pragma unroll
    for (int k = 0; k < 4; ++k) { int d = pd - (tchunk * 4 + k); dd2[k] = d * d; }
#pragma unroll
    for (int j = 0; j < 8; ++j) { int h = ph - (4 * j + tg); dh2[j] = h * h; }

    int best = -1;
#pragma unroll
    for (int i = 0; i < 32; ++i) {
        int2 te = s_te[tg + 4 * i];
        int q = max(pe.y - te.x, te.y - pe.x);
        int cand = dd2[i >> 3] + dh2[i & 7] + q * q;
        best = (te.y >= 0) ? max(best, cand) : best;   // skip empty target col
    }
    if (pe.y < 0) best = -1;              // empty pred column: discard

    // block reduce (8 waves)
#pragma unroll
    for (int m = 32; m >= 1; m >>= 1) best = max(best, __shfl_xor(best, m, 64));
    if ((tid & 63) == 0) s_red[tid >> 6] = best;
    __syncthreads();

    // ---- Phase C: handshake + finish, wave 0 only (no extra barriers) ----
    if (tid < 64) {
        int win = 0;
        if (tid == 0) {
            int mx = s_red[0];
#pragma unroll
            for (int i = 1; i < 8; ++i) mx = max(mx, s_red[i]);
            __hip_atomic_store(&bmax[bid], mx, __ATOMIC_RELAXED,
                               __HIP_MEMORY_SCOPE_AGENT);
            // partial must be at the coherent point before our ticket lands
            asm volatile("s_waitcnt vmcnt(0)" ::: "memory");
            int g = bid >> 4;             // 16 groups of 16 blocks
            unsigned o1 = atomicAdd(&gcnt[g * 32], 1u);   // own 128B line
            if (((o1 + 1u) & 15u) == 0u) {
                // branch on o1 already waited for the gcnt RMW return, which
                // orders this add after it (and after all 16 group partials)
                unsigned o2 = atomicAdd(fcnt, 1u);        // own line
                win = (((o2 + 1u) & 15u) == 0u) ? 1 : 0;  // last group overall
            }
        }
        win = __shfl(win, 0, 64);         // in-wave broadcast, no barrier
        if (win) {
            // lane l holds bids 4l..4l+3; sample = l>>4 (64 bids per sample)
            int b0 = tid * 4;
            int m0 = __hip_atomic_load(&bmax[b0 + 0], __ATOMIC_RELAXED,
                                       __HIP_MEMORY_SCOPE_AGENT);
            int m1 = __hip_atomic_load(&bmax[b0 + 1], __ATOMIC_RELAXED,
                                       __HIP_MEMORY_SCOPE_AGENT);
            int m2 = __hip_atomic_load(&bmax[b0 + 2], __ATOMIC_RELAXED,
                                       __HIP_MEMORY_SCOPE_AGENT);
            int m3 = __hip_atomic_load(&bmax[b0 + 3], __ATOMIC_RELAXED,
                                       __HIP_MEMORY_SCOPE_AGENT);
            int m = max(max(m0, m1), max(m2, m3));
#pragma unroll
            for (int k = 8; k >= 1; k >>= 1) m = max(m, __shfl_xor(m, k, 64));
            float hd = (m < 0) ? INFINITY : sqrtf((float)m);
            // lanes 0,16,32,48 hold samples 0..3
            float ssum = __shfl(hd, 0, 64) + __shfl(hd, 16, 64) +
                         __shfl(hd, 32, 64) + __shfl(hd, 48, 64);
            if (tid == 0) out[0] = ssum * (1.0f / NB);
        }
    }
}

extern "C" void kernel_launch(void* const* d_in, const int* in_sizes, int n_in,
                              void* d_out, int out_size, void* d_ws, size_t ws_size,
                              hipStream_t stream) {
    const float* logits  = (const float*)d_in[0];
    const float* targets = (const float*)d_in[1];
    float* out = (float*)d_out;

    char* ws = (char*)d_ws;               // all no-init (see kernel comment)
    int* bmax = (int*)ws;                                 // 256 ints (1 KB)
    unsigned* gcnt = (unsigned*)(ws + 1024);              // 16 x 128B-padded
    unsigned* fcnt = (unsigned*)(ws + 1024 + 16 * 128);   // own line

    hd_one<<<NBLK, 512, 0, stream>>>(logits, targets, bmax, gcnt, fcnt, out);
}